// Round 3
// baseline (300.885 us; speedup 1.0000x reference)
//
#include <hip/hip_runtime.h>

#define BB 16
#define TT 2000
#define FF 481
#define NDF_ 96
#define ORDER_ 5
#define ROW_F 962          // floats per (b,t) row of spec/out
#define COEF_ROW_F 960     // floats per (b,t) row of coefs

typedef float floatx4 __attribute__((ext_vector_type(4)));

// ---------------------------------------------------------------------------
// Kernel 1: flat float4 streaming copy of spec -> out (entire array).
// 30,784,000 floats = exactly 7,696,000 float4, base 16B-aligned.
// Nontemporal: read-once / write-once streaming, don't pollute L2.
// ---------------------------------------------------------------------------
__global__ __launch_bounds__(256) void copy_kernel(
    const floatx4* __restrict__ src, floatx4* __restrict__ dst, int n4)
{
    int idx    = blockIdx.x * 256 + threadIdx.x;
    int stride = gridDim.x * 256;
    for (int i = idx; i < n4; i += stride) {
        floatx4 v = __builtin_nontemporal_load(&src[i]);
        __builtin_nontemporal_store(v, &dst[i]);
    }
}

// ---------------------------------------------------------------------------
// Kernel 2: 5-tap complex FIR + alpha blend on bins [0,96), overwrites the
// DF region of out. Block = 768 threads = 8 consecutive t-rows x 96 lanes,
// so tap reads (t-4..t) overlap heavily within the block (L1/L2 reuse).
// ---------------------------------------------------------------------------
__global__ __launch_bounds__(768) void df_kernel(
    const float* __restrict__ spec,
    const float* __restrict__ coefs,
    const float* __restrict__ alpha,
    float* __restrict__ out)
{
    const int b  = blockIdx.x / 250;          // 16 b's x 250 t-chunks
    const int t0 = (blockIdx.x - b * 250) * 8;
    const int r  = threadIdx.x / 96;          // row within chunk [0,8)
    const int f  = threadIdx.x - r * 96;      // DF bin [0,96)
    const int t  = t0 + r;
    const int bt = b * TT + t;

    const float a   = alpha[bt];
    const float oma = 1.0f - a;

    float acc_re = 0.0f, acc_im = 0.0f;
    const float2* cbase = (const float2*)(coefs + (long)bt * COEF_ROW_F + f * 2);
    #pragma unroll
    for (int k = 0; k < ORDER_; ++k) {
        const int tk = t - (ORDER_ - 1) + k;
        float2 x = make_float2(0.0f, 0.0f);
        if (tk >= 0) {
            x = *(const float2*)(spec + ((long)b * TT + tk) * ROW_F + f * 2);
        }
        const float2 c = cbase[k * NDF_];
        acc_re += x.x * c.x - x.y * c.y;
        acc_im += x.y * c.x + x.x * c.y;
    }

    const long row = (long)bt * ROW_F;
    const float2 s = *(const float2*)(spec + row + f * 2);
    float2 o;
    o.x = acc_re * a + s.x * oma;
    o.y = acc_im * a + s.y * oma;
    *(float2*)(out + row + f * 2) = o;
}

extern "C" void kernel_launch(void* const* d_in, const int* in_sizes, int n_in,
                              void* d_out, int out_size, void* d_ws, size_t ws_size,
                              hipStream_t stream) {
    const float* spec  = (const float*)d_in[0];
    const float* coefs = (const float*)d_in[1];
    const float* alpha = (const float*)d_in[2];
    float* out = (float*)d_out;

    const int n4 = (BB * TT * FF * 2) / 4;   // 7,696,000 float4
    copy_kernel<<<8192, 256, 0, stream>>>((const floatx4*)spec, (floatx4*)out, n4);

    df_kernel<<<BB * 250, 768, 0, stream>>>(spec, coefs, alpha, out);
}